// Round 1
// baseline (211.941 us; speedup 1.0000x reference)
//
#include <hip/hip_runtime.h>
#include <cstdint>
#include <cstddef>

// ---------------------------------------------------------------------------
// Style2ResidualBlock1DSrc: modulated conv1d (StyleGAN2-style) on MI355X.
//   s = concat(c_src,c_trg) @ (style_w * LIN_SCALE)^T + style_b        [16,512]
//   w = CONV_SCALE * weight * s  ; demod over (i,k); w *= demod        [16,512,512,3]
//   out[b,o,t] = sum_{i,k} w[b,o,i,k] * x[b,i,t+k-1]  (same padding)   [16,512,2048]
// Implemented as bf16 MFMA GEMMs: per batch, 3 accumulating GEMMs (one per tap)
// with xT pre-transposed/padded to [t][i] bf16 so both operands are K-contiguous.
// ---------------------------------------------------------------------------

#define LIN_SCALE  0.0625f           // 1/sqrt(256)
#define CONV_SCALE 0.014731391f      // 1/sqrt(512*9)

#define B_   16
#define CIN  512
#define COUT 512
#define T_   2048
#define TP   2050                    // T + 2 pad rows

typedef __bf16 bf16x8 __attribute__((ext_vector_type(8)));
typedef float  f32x4  __attribute__((ext_vector_type(4)));

__device__ inline unsigned short f2bf(float f) {
  __bf16 h = (__bf16)f;              // RNE fptrunc
  return __builtin_bit_cast(unsigned short, h);
}

// ---------------- 1. style linear: s[b][i] ----------------
__global__ void style_kernel(const float* __restrict__ c_src,
                             const float* __restrict__ c_trg,
                             const float* __restrict__ sw,
                             const float* __restrict__ sb,
                             float* __restrict__ s) {
  __shared__ float c[256];
  const int b = blockIdx.x;
  const int tid = threadIdx.x;       // 512 threads, one output each
  if (tid < 128)       c[tid] = c_src[b * 128 + tid];
  else if (tid < 256)  c[tid] = c_trg[b * 128 + tid - 128];
  __syncthreads();
  float acc = 0.f;
  const float* row = sw + (size_t)tid * 256;
  #pragma unroll 8
  for (int j = 0; j < 256; ++j) acc += row[j] * c[j];
  s[b * 512 + tid] = acc * LIN_SCALE + sb[tid];
}

// ---------------- 2. modulate + demodulate -> bf16 W[b][tap][o][i] ----------------
__global__ __launch_bounds__(256) void modw_kernel(const float* __restrict__ weight,
                                                   const float* __restrict__ s,
                                                   unsigned short* __restrict__ Wm) {
  const int o = blockIdx.x, b = blockIdx.y;
  const int tid = threadIdx.x;
  __shared__ float sv[512];
  __shared__ float red[5];
  sv[tid]       = s[b * 512 + tid];
  sv[tid + 256] = s[b * 512 + tid + 256];
  __syncthreads();

  // thread handles 6 consecutive elements of weight[o][:][:] (i = 2*tid, 2*tid+1)
  const float* wrow = weight + (size_t)o * 1536 + tid * 6;
  const int i0 = 2 * tid;
  float v[6]; float ss = 0.f;
  #pragma unroll
  for (int q = 0; q < 6; ++q) {
    const int i = i0 + (q >= 3);
    const float w = wrow[q] * CONV_SCALE * sv[i];
    v[q] = w; ss += w * w;
  }
  // block reduce (4 waves of 64)
  #pragma unroll
  for (int off = 32; off > 0; off >>= 1) ss += __shfl_down(ss, off, 64);
  if ((tid & 63) == 0) red[tid >> 6] = ss;
  __syncthreads();
  if (tid == 0) red[4] = rsqrtf(red[0] + red[1] + red[2] + red[3] + 1e-8f);
  __syncthreads();
  const float dem = red[4];

  // write W[b][k][o][i] bf16 (i contiguous)
  #pragma unroll
  for (int q = 0; q < 6; ++q) {
    const int i = i0 + (q >= 3);
    const int k = (q >= 3) ? (q - 3) : q;
    Wm[(((size_t)b * 3 + k) * 512 + o) * 512 + i] = f2bf(v[q] * dem);
  }
}

// ---------------- 3. transpose + pad + bf16: xT[b][1+t][i] = x[b][i][t] ----------------
__global__ __launch_bounds__(256) void transpose_kernel(const float* __restrict__ x,
                                                        unsigned short* __restrict__ xT) {
  __shared__ float tile[64][65];     // +1 pad: conflict-free transposed reads
  const int b = blockIdx.z, i0 = blockIdx.y * 64, t0 = blockIdx.x * 64;
  const int c  = threadIdx.x & 63;
  const int r0 = threadIdx.x >> 6;   // 0..3
  const float* xb = x + ((size_t)b * CIN + i0) * T_ + t0;
  #pragma unroll
  for (int rr = 0; rr < 64; rr += 4) {
    const int r = rr + r0;
    tile[r][c] = xb[(size_t)r * T_ + c];   // coalesced along t
  }
  __syncthreads();
  unsigned short* xTb = xT + ((size_t)b * TP + 1 + t0) * CIN + i0;
  #pragma unroll
  for (int rr = 0; rr < 64; rr += 4) {
    const int t = rr + r0;
    xTb[(size_t)t * CIN + c] = f2bf(tile[c][t]);   // coalesced along i
  }
}

// zero pad rows t=0 and t=2049 of xT
__global__ void zpad_kernel(unsigned short* __restrict__ xT) {
  const int b = blockIdx.x;
  const size_t base = (size_t)b * TP * CIN;
  for (int j = threadIdx.x; j < CIN; j += 256) {
    xT[base + j] = 0;
    xT[base + (size_t)(TP - 1) * CIN + j] = 0;
  }
}

// ---------------- 4. main GEMM: out[b][o][t] = sum_tap W_tap @ xT(shifted) ----------------
// 128x128 tile, BK=64, 256 threads = 4 waves, each wave 64x64 (4x4 MFMA 16x16x32 frags).
#define BM 128
#define BN 128
#define BK 64

__global__ __launch_bounds__(256, 2) void gemm_kernel(const unsigned short* __restrict__ Wm,
                                                      const unsigned short* __restrict__ xT,
                                                      float* __restrict__ out) {
  __shared__ unsigned short lA[BM * BK];   // 16 KB: A tile [o_row][i]
  __shared__ unsigned short lB[BN * BK];   // 16 KB: B tile [t_row][i]

  const int b  = blockIdx.z;
  const int o0 = blockIdx.y * BM;
  const int t0 = blockIdx.x * BN;
  const int tid  = threadIdx.x;
  const int lane = tid & 63;
  const int wm = (threadIdx.x >> 6 & 1) * 64;   // wave row (o) offset
  const int wn = (threadIdx.x >> 7) * 64;       // wave col (t) offset

  // staging: thread -> 16B chunk; round p adds 32 rows
  const int srow = tid >> 3;           // 0..31
  const int scol = (tid & 7) * 8;      // element offset within 64-wide row
  const unsigned short* gW = Wm + (size_t)b * 3 * 512 * 512 + (size_t)(o0 + srow) * 512 + scol;
  const unsigned short* gX = xT + (size_t)b * TP * CIN + (size_t)(t0 + srow) * CIN + scol;
  unsigned short* lAp = &lA[tid * 8];  // dest chunk, lane-contiguous within wave
  unsigned short* lBp = &lB[tid * 8];

  f32x4 acc[4][4];
  #pragma unroll
  for (int i = 0; i < 4; ++i)
    #pragma unroll
    for (int j = 0; j < 4; ++j) acc[i][j] = (f32x4){0.f, 0.f, 0.f, 0.f};

  for (int kk = 0; kk < 24; ++kk) {
    const int tap = kk >> 3;
    const int i0  = (kk & 7) * 64;
    const size_t offA = (size_t)tap * 512 * 512 + i0;   // W tap plane + i block
    const size_t offX = (size_t)tap * CIN + i0;          // t shift = tap rows + i block
    __syncthreads();                    // LDS reuse: previous compute done
    #pragma unroll
    for (int p = 0; p < 4; ++p)
      __builtin_amdgcn_global_load_lds(
          (const __attribute__((address_space(1))) void*)(gW + offA + (size_t)p * 32 * 512),
          (__attribute__((address_space(3))) void*)(lAp + p * 2048), 16, 0, 0);
    #pragma unroll
    for (int p = 0; p < 4; ++p)
      __builtin_amdgcn_global_load_lds(
          (const __attribute__((address_space(1))) void*)(gX + offX + (size_t)p * 32 * CIN),
          (__attribute__((address_space(3))) void*)(lBp + p * 2048), 16, 0, 0);
    __syncthreads();                    // staging visible (implies vmcnt(0))

    #pragma unroll
    for (int s = 0; s < 2; ++s) {
      const int ko = s * 32 + (lane >> 4) * 8;
      bf16x8 af[4], bfr[4];
      #pragma unroll
      for (int mi = 0; mi < 4; ++mi)
        af[mi] = *(const bf16x8*)&lA[(wm + mi * 16 + (lane & 15)) * BK + ko];
      #pragma unroll
      for (int ni = 0; ni < 4; ++ni)
        bfr[ni] = *(const bf16x8*)&lB[(wn + ni * 16 + (lane & 15)) * BK + ko];
      #pragma unroll
      for (int mi = 0; mi < 4; ++mi)
        #pragma unroll
        for (int ni = 0; ni < 4; ++ni)
          acc[mi][ni] = __builtin_amdgcn_mfma_f32_16x16x32_bf16(af[mi], bfr[ni], acc[mi][ni], 0, 0, 0);
    }
  }

  // epilogue: D row = (lane>>4)*4 + reg, col = lane&15  (m89 mapping)
  float* ob = out + ((size_t)b * COUT + o0 + wm) * T_ + t0 + wn;
  const int rrow = (lane >> 4) * 4;
  const int ccol = lane & 15;
  #pragma unroll
  for (int mi = 0; mi < 4; ++mi)
    #pragma unroll
    for (int ni = 0; ni < 4; ++ni)
      #pragma unroll
      for (int r = 0; r < 4; ++r)
        ob[(size_t)(mi * 16 + rrow + r) * T_ + ni * 16 + ccol] = acc[mi][ni][r];
}

// ---------------------------------------------------------------------------
extern "C" void kernel_launch(void* const* d_in, const int* in_sizes, int n_in,
                              void* d_out, int out_size, void* d_ws, size_t ws_size,
                              hipStream_t stream) {
  const float* x       = (const float*)d_in[0];   // [16,512,2048]
  const float* c_src   = (const float*)d_in[1];   // [16,128]
  const float* c_trg   = (const float*)d_in[2];   // [16,128]
  const float* style_w = (const float*)d_in[3];   // [512,256]
  const float* style_b = (const float*)d_in[4];   // [512]
  const float* weight  = (const float*)d_in[5];   // [1,512,512,3]
  float* out = (float*)d_out;

  // workspace layout (assumes ws_size >= ~59 MB):
  //   s_buf  fp32 [16][512]            @ 0        (32 KB)
  //   Wm     bf16 [16][3][512][512]    @ 32768    (25,165,824 B)
  //   xT     bf16 [16][2050][512]      @ 25198592 (33,587,200 B)
  char* ws = (char*)d_ws;
  float* s_buf          = (float*)ws;
  unsigned short* Wm    = (unsigned short*)(ws + 32768);
  unsigned short* xTbuf = (unsigned short*)(ws + 32768 + 25165824);

  style_kernel<<<dim3(B_), 512, 0, stream>>>(c_src, c_trg, style_w, style_b, s_buf);
  modw_kernel<<<dim3(COUT, B_), 256, 0, stream>>>(weight, s_buf, Wm);
  transpose_kernel<<<dim3(T_ / 64, CIN / 64, B_), 256, 0, stream>>>(x, xTbuf);
  zpad_kernel<<<dim3(B_), 256, 0, stream>>>(xTbuf);
  gemm_kernel<<<dim3(T_ / BN, COUT / BM, B_), 256, 0, stream>>>(Wm, xTbuf, out);
}